// Round 2
// baseline (81.010 us; speedup 1.0000x reference)
//
#include <hip/hip_runtime.h>
#include <hip/hip_fp16.h>
#include <stdint.h>

// out[c,b,g] = sum_{s<8} prod_{l<3} x[b, I[c,g,s,l]]
#define Cc 16
#define Gg 8192
#define Ss 8
#define Ll 3
#define Bb 32

#define BH 4                  // b-rows per slice (f16) -> 8 B per g column
#define NZ (Bb / BH)          // 8 slices
#define THREADS 512
#define ITERS 2
#define GCH (THREADS * ITERS) // 1024 g per block
#define NGC (Gg / GCH)        // 8 g-chunks

// Evaluate one (c,g): 24 indices in q[6], 24 natural-layout ds_read_b64
// gathers (4 f16 b-values per index). Two 12-index half-batches cap live
// gather registers at 24.
__device__ __forceinline__ void clause_eval(const uint2* __restrict__ xl2,
                                            const int4 q[6], float acc[4]) {
    #pragma unroll
    for (int h = 0; h < 2; ++h) {
        const int4 qa = q[3 * h + 0];
        const int4 qb = q[3 * h + 1];
        const int4 qc = q[3 * h + 2];
        int idx[12] = {qa.x, qa.y, qa.z, qa.w,
                       qb.x, qb.y, qb.z, qb.w,
                       qc.x, qc.y, qc.z, qc.w};
        uint2 r[12];
        #pragma unroll
        for (int k = 0; k < 12; ++k)             // independent ds_read_b64
            r[k] = xl2[(uint32_t)idx[k]];
        #pragma unroll
        for (int s = 0; s < 4; ++s) {
            const uint2 ra = r[3 * s + 0];
            const uint2 rb = r[3 * s + 1];
            const uint2 rd = r[3 * s + 2];
            __half2 p0 = __hmul2(__hmul2(*(const __half2*)&ra.x,
                                         *(const __half2*)&rb.x),
                                 *(const __half2*)&rd.x);   // b0,b1
            __half2 p1 = __hmul2(__hmul2(*(const __half2*)&ra.y,
                                         *(const __half2*)&rb.y),
                                 *(const __half2*)&rd.y);   // b2,b3
            float2 f0 = __half22float2(p0);
            float2 f1 = __half22float2(p1);
            acc[0] += f0.x;
            acc[1] += f0.y;
            acc[2] += f1.x;
            acc[3] += f1.y;
        }
    }
}

// Pipelined structure: 1024 blocks x 512 threads, LDS image 64 KB
// (4 b-rows f16, all G) -> TWO blocks co-resident per CU. Co-resident blocks
// run phase-shifted, so block n+1's staging (global pipe + ds_write) overlaps
// block n's eval (ds_read + VALU) -- the phase serialization that capped the
// 128 KB / 1-block-per-CU version.
//  - 16 waves/CU = 4 waves/SIMD, VGPR budget 128, ~90 live regs (no spill).
//  - natural uint2 layout: gather address = idx, bank-pair bin = idx & 15
//    (same conflict profile as the old swizzle, zero address math).
//  - XCD-bijective swizzle: 8 consecutive logical blocks = the 8 z-twins of
//    one (c, g-chunk) -> their identical I reads hit one XCD's L2; each c
//    lives on exactly one XCD, so I is fetched from HBM once.
__global__ __launch_bounds__(THREADS, 4) void clause_f16_p2(
        const float* __restrict__ x, const int* __restrict__ I,
        float* __restrict__ out) {
    __shared__ uint2 xl[Gg];                       // 64 KB
    const int tid = threadIdx.x;

    // 1024 blocks, 8 XCDs, 128 blocks/XCD; bijective since 1024 % 8 == 0.
    const int lb = (blockIdx.x & 7) * (1024 / 8) + (blockIdx.x >> 3);
    const int zh = lb & (NZ - 1);                  // slice
    const int gc = (lb >> 3) & (NGC - 1);          // g-chunk
    const int c  = lb >> 6;
    const int gbase = gc * GCH;

    // Prefetch both iterations' indices early (HBM latency hides under stage).
    const int g0 = gbase + tid;
    const int g1 = gbase + THREADS + tid;
    const int4* ip0 = (const int4*)(I + ((size_t)c * Gg + g0) * (Ss * Ll));
    const int4* ip1 = (const int4*)(I + ((size_t)c * Gg + g1) * (Ss * Ll));
    int4 q0[6], q1[6];
    #pragma unroll
    for (int k = 0; k < 6; ++k) q0[k] = ip0[k];
    #pragma unroll
    for (int k = 0; k < 6; ++k) q1[k] = ip1[k];

    // Stage slice zh (b-rows 4zh..4zh+3): each thread packs 2 consecutive g
    // columns per iteration -> float2 global loads (coalesced 512 B/wave) and
    // one ds_write_b128 (lane-stride 16 B, conflict-free).
    {
        const float* xs = x + (size_t)(BH * zh) * Gg;
        #pragma unroll 4
        for (int k = 0; k < Gg / (2 * THREADS); ++k) {   // 8 iterations
            const int g = 2 * (tid + k * THREADS);
            float2 v0 = *(const float2*)&xs[g];              // row b0
            float2 v1 = *(const float2*)&xs[Gg + g];         // row b1
            float2 v2 = *(const float2*)&xs[2 * (size_t)Gg + g];
            float2 v3 = *(const float2*)&xs[3 * (size_t)Gg + g];
            __half2 a01 = __floats2half2_rn(v0.x, v1.x);     // column g
            __half2 a23 = __floats2half2_rn(v2.x, v3.x);
            __half2 b01 = __floats2half2_rn(v0.y, v1.y);     // column g+1
            __half2 b23 = __floats2half2_rn(v2.y, v3.y);
            uint4 w = make_uint4(*(const uint32_t*)&a01, *(const uint32_t*)&a23,
                                 *(const uint32_t*)&b01, *(const uint32_t*)&b23);
            *(uint4*)&xl[g] = w;
        }
    }

    __syncthreads();                               // the ONE barrier

    float* opb = out + ((size_t)(c * Bb + BH * zh)) * Gg;

    {
        float acc[4] = {0, 0, 0, 0};
        clause_eval(xl, q0, acc);
        #pragma unroll
        for (int j = 0; j < 4; ++j)                // lane-consecutive g -> coalesced
            opb[(size_t)j * Gg + g0] = acc[j];
    }
    {
        float acc[4] = {0, 0, 0, 0};
        clause_eval(xl, q1, acc);
        #pragma unroll
        for (int j = 0; j < 4; ++j)
            opb[(size_t)j * Gg + g1] = acc[j];
    }
}

extern "C" void kernel_launch(void* const* d_in, const int* in_sizes, int n_in,
                              void* d_out, int out_size, void* d_ws, size_t ws_size,
                              hipStream_t stream) {
    const float* x = (const float*)d_in[0];
    const int* I = (const int*)d_in[1];
    float* out = (float*)d_out;
    (void)d_ws; (void)ws_size;                     // no workspace needed

    const int grid = Cc * NGC * NZ;                // 1024 blocks
    clause_f16_p2<<<grid, THREADS, 0, stream>>>(x, I, out);
}